// Round 2
// baseline (199.797 us; speedup 1.0000x reference)
//
#include <hip/hip_runtime.h>

#define NPTS 65536
#define NB 32
#define H 256
#define K2E 2.8853900817779268f   // 2*log2(e): tanh(z)=1-2/(exp2(K2E*z)+1)

typedef __attribute__((ext_vector_type(8))) short bhalf8;   // 8 bf16 = 4 VGPRs
typedef __attribute__((ext_vector_type(4))) float f32x4;

union BHU { bhalf8 h; uint u[4]; };

__device__ __forceinline__ float bf2f(ushort u) {
  union { uint x; float f; } c; c.x = ((uint)u) << 16; return c.f;
}
__device__ __forceinline__ ushort f2bf(float f) {            // RNE (final outputs only)
  uint x = __float_as_uint(f);
  uint r = x + 0x7FFFu + ((x >> 16) & 1u);
  return (ushort)(r >> 16);
}
__device__ __forceinline__ uint packrne(float a, float b) {
  return (uint)f2bf(a) | ((uint)f2bf(b) << 16);
}
// truncating bf16 — MFMA inputs / LDS intermediates only
__device__ __forceinline__ ushort trunc1(float f) {
  return (ushort)(__float_as_uint(f) >> 16);
}
__device__ __forceinline__ uint packtr(float a, float b) {
  return (__float_as_uint(a) >> 16) | (__float_as_uint(b) & 0xFFFF0000u);
}
// tanh with pre-folded 2*log2e arg: v_exp + v_add + v_rcp + v_fma (no div sequence!)
__device__ __forceinline__ float tanh_pf(float z2e) {
  float e = exp2f(z2e);
  float r = __builtin_amdgcn_rcpf(e + 1.0f);
  return fmaf(-2.0f, r, 1.0f);
}

// dtype detect from W1 bit pattern (wave-uniform)
__device__ __forceinline__ bool detect_bf16(const void* W1) {
  const uint4* p = (const uint4*)W1;
  int cnt = 0;
#pragma unroll
  for (int i = 0; i < 8; i++) {
    uint4 v = p[i];
    uint d[4] = {v.x, v.y, v.z, v.w};
#pragma unroll
    for (int k = 0; k < 4; k++) {
      int e = (d[k] >> 7) & 0xFF;                 // exponent of low halfword
      cnt += (e >= 0x70 && e <= 0x7E) ? 1 : 0;
    }
  }
  return cnt >= 16;
}

template<bool B16> __device__ __forceinline__ float LD(const void* p, int i) {
  if constexpr (B16) return bf2f(((const ushort*)p)[i]);
  else               return ((const float*)p)[i];
}
template<bool B16> __device__ __forceinline__ void ST(void* p, int i, float v) {
  if constexpr (B16) ((ushort*)p)[i] = f2bf(v);
  else               ((float*)p)[i] = v;
}

// Pre-swizzle W1 [256][256], W2 [256][32] into MFMA B-frag order (bf16):
// frag(ct,kk): lane l=q*16+r holds B[kk*32+q*8+j][ct*16+r], j=0..7.
__global__ void swz_kernel(const void* W1, const void* W2,
                           ushort* __restrict__ W1s, ushort* __restrict__ W2s) {
  int gid = blockIdx.x * 256 + threadIdx.x;
  bool b16 = detect_bf16(W1);
  if (gid < 65536) {
    int r = gid & 15, q = (gid >> 4) & 3, j = (gid >> 6) & 7;
    int kk = (gid >> 9) & 7, ct = gid >> 12;
    int src = (kk * 32 + q * 8 + j) * H + ct * 16 + r;
    int dst = ((ct * 8 + kk) * 64 + q * 16 + r) * 8 + j;
    float v = b16 ? bf2f(((const ushort*)W1)[src]) : ((const float*)W1)[src];
    W1s[dst] = f2bf(v);
  } else {
    int g2 = gid - 65536;
    int r = g2 & 15, q = (g2 >> 4) & 3, j = (g2 >> 6) & 7;
    int kk = (g2 >> 9) & 7, ct = (g2 >> 12) & 1;
    int src = (kk * 32 + q * 8 + j) * NB + ct * 16 + r;
    int dst = ((ct * 8 + kk) * 64 + q * 16 + r) * 8 + j;
    float v = b16 ? bf2f(((const ushort*)W2)[src]) : ((const float*)W2)[src];
    W2s[dst] = f2bf(v);
  }
}

#define PPITCH 40    // bf16 cols: 80B rows, b128-aligned

// LDS layout:
//   pairw: wave-private h1 chunk (rows 0..31 reused for sin/cos in epilogue)
//   w1st : 3-buffer ring of one-ct W1 B-frag chunks (8KB each), block-shared,
//          filled by global_load_lds (linear layout == frag layout, rule-21 OK)
struct Smem {
  alignas(16) ushort pairw[4][48 * PPITCH];  // 15360 B
  alignas(16) ushort w1st[3][4096];          // 24576 B
  alignas(16) ushort lamTf[2 * 64 * 8];      //  2048 B lambda^T B-frags
  alignas(16) float  w0d[H], w0e[H], b0e[H], b1e[H]; // 4096 B (w0d = 0.1*w0 pre-folded)
  alignas(16) float  b2c[NB], lamMc[NB], lamDc[NB]; // 384 B
};                                           // 46464 B -> 3 blocks/CU LDS-wise

// Stage one ct's 8KB W1-frag chunk into an LDS ring buffer.
// Dest is wave-uniform base (HW adds lane*16B); src is per-lane. 2 issues/wave.
__device__ __forceinline__ void stage_ct(const ushort* __restrict__ W1s,
                                         ushort* buf, int ct, int wave, int lane) {
#pragma unroll
  for (int c = 0; c < 2; c++) {
    const ushort* src = W1s + ct * 4096 + (wave * 2 + c) * 512 + lane * 8;
    ushort* dst = buf + (wave * 2 + c) * 512;   // wave-uniform
    __builtin_amdgcn_global_load_lds(
        (const __attribute__((address_space(1))) unsigned int*)src,
        (__attribute__((address_space(3))) unsigned int*)dst, 16, 0, 0);
  }
}

// GEMM1 for one ct: 8 ds_read_b128 + 24 MFMA, setprio around the MFMA cluster (T5)
__device__ __forceinline__ void gemm1(const ushort* __restrict__ buf, int lane,
                                      const bhalf8* a0f, const bhalf8* a1f,
                                      const bhalf8* a2f,
                                      f32x4& c0, f32x4& c1, f32x4& c2) {
  f32x4 z = {0.f, 0.f, 0.f, 0.f};
  c0 = z; c1 = z; c2 = z;
  bhalf8 bf[8];
#pragma unroll
  for (int kk = 0; kk < 8; kk++)
    bf[kk] = *(const bhalf8*)(buf + (kk * 64 + lane) * 8);
  __builtin_amdgcn_s_setprio(1);
#pragma unroll
  for (int kk = 0; kk < 8; kk++) {
    c0 = __builtin_amdgcn_mfma_f32_16x16x32_bf16(a0f[kk], bf[kk], c0, 0, 0, 0);
    c1 = __builtin_amdgcn_mfma_f32_16x16x32_bf16(a1f[kk], bf[kk], c1, 0, 0, 0);
    c2 = __builtin_amdgcn_mfma_f32_16x16x32_bf16(a2f[kk], bf[kk], c2, 0, 0, 0);
  }
  __builtin_amdgcn_s_setprio(0);
}

// tanh chain for one ct -> pw column lc
__device__ __forceinline__ void chain(ushort* pw, float b1v, int q, int lc,
                                      const f32x4& c0, const f32x4& c1,
                                      const f32x4& c2) {
#pragma unroll
  for (int i = 0; i < 4; i++) {
    float hv  = tanh_pf(fmaf(c0[i], K2E, b1v));
    float s2  = 1.0f - hv * hv;
    float hd  = s2 * c1[i];
    float hdd = s2 * c2[i] - 2.0f * hv * hd * c1[i];
    int row = q * 4 + i;
    pw[row * PPITCH + lc]        = trunc1(hv);
    pw[(16 + row) * PPITCH + lc] = trunc1(hd);
    pw[(32 + row) * PPITCH + lc] = trunc1(hdd);
  }
}

template<bool B16>
__device__ void pinn_body(Smem& sm,
                          const void* timeP, const void* powerP,
                          const void* W0, const void* b0,
                          const void* b1, const void* b2,
                          const void* lam_m, const void* lam_d,
                          const void* lam_b, const void* bwi,
                          const ushort* __restrict__ W1s, void* outP) {
  const int tid = threadIdx.x;
  const int wave = tid >> 6, lane = tid & 63;
  const int q = lane >> 4, r = lane & 15;
  const ushort* W2s = W1s + H * H;

  // issue ring prologue stages first — latency hides under the whole preamble
  stage_ct(W1s, &sm.w1st[0][0], 0, wave, lane);
  stage_ct(W1s, &sm.w1st[1][0], 1, wave, lane);

  // ================= preamble (one barrier) =================
  if (tid < 128) {   // lambda^T B-frags: lane holds lam_b[ct*16+r][q*8+j]
    int ct = tid >> 6, l2 = tid & 63, qq = l2 >> 4, rr = l2 & 15;
    BHU t;
#pragma unroll
    for (int j = 0; j < 8; j += 2)
      t.u[j >> 1] = packrne(LD<B16>(lam_b, (ct * 16 + rr) * NB + qq * 8 + j),
                            LD<B16>(lam_b, (ct * 16 + rr) * NB + qq * 8 + j + 1));
    *(bhalf8*)(sm.lamTf + tid * 8) = t.h;
  }
  if (tid < H) {
    float w0v = LD<B16>(W0, tid);
    sm.w0d[tid] = 0.1f * w0v;          // pre-fold the 2/TMAX chain-rule factor
    sm.w0e[tid] = K2E * w0v;
    sm.b0e[tid] = K2E * LD<B16>(b0, tid);
    sm.b1e[tid] = K2E * LD<B16>(b1, tid);
  }
  if (tid < NB) {
    sm.b2c[tid]   = LD<B16>(b2, tid);
    sm.lamMc[tid] = LD<B16>(lam_m, tid) * LD<B16>(bwi, tid);
    sm.lamDc[tid] = LD<B16>(lam_d, tid);
  }
  __syncthreads();   // full drain once — prologue stages complete here too

  // ================= per-wave sample tile =================
  const int s0 = (blockIdx.x * 4 + wave) * 16;
  ushort* pw = &sm.pairw[wave][0];

  float t = LD<B16>(timeP, s0 + r);
  float x = t * 0.1f - 1.0f;               // 2t/TMAX - 1, TMAX = 20

  // ---- A-frags in registers: lane holds Ach[r][kk*32+q*8+j] ----
  bhalf8 a0f[8], a1f[8], a2f[8];
#pragma unroll
  for (int kk = 0; kk < 8; kk++) {
    int k0 = kk * 32 + q * 8;
    float4 wA = *(const float4*)&sm.w0d[k0];
    float4 wB = *(const float4*)&sm.w0d[k0 + 4];
    float4 eA = *(const float4*)&sm.w0e[k0];
    float4 eB = *(const float4*)&sm.w0e[k0 + 4];
    float4 bA = *(const float4*)&sm.b0e[k0];
    float4 bB = *(const float4*)&sm.b0e[k0 + 4];
    float w0dv[8] = {wA.x, wA.y, wA.z, wA.w, wB.x, wB.y, wB.z, wB.w};
    float w0ev[8] = {eA.x, eA.y, eA.z, eA.w, eB.x, eB.y, eB.z, eB.w};
    float b0ev[8] = {bA.x, bA.y, bA.z, bA.w, bB.x, bB.y, bB.z, bB.w};
    BHU t0, t1, t2;
    float vv[8], d1v[8], d2v[8];
#pragma unroll
    for (int j = 0; j < 8; j++) {
      float v = tanh_pf(fmaf(x, w0ev[j], b0ev[j]));
      float cc = w0dv[j];                       // = w0*0.1 (pre-folded)
      float s2 = 1.0f - v * v;
      vv[j] = v; d1v[j] = s2 * cc; d2v[j] = -2.0f * v * d1v[j] * cc;
    }
#pragma unroll
    for (int j = 0; j < 8; j += 2) {
      t0.u[j >> 1] = packtr(vv[j], vv[j + 1]);
      t1.u[j >> 1] = packtr(d1v[j], d1v[j + 1]);
      t2.u[j >> 1] = packtr(d2v[j], d2v[j + 1]);
    }
    a0f[kk] = t0.h; a1f[kk] = t1.h; a2f[kk] = t2.h;
  }

  // ---- fused GEMM1 -> tanh chain -> GEMM2 over LDS W1 ring ----
  // Sync discipline (T3/T4): one {vmcnt(2); s_barrier} per ct, counted — never
  // drains the stage queue. 3-buffer rotation makes a single barrier race-free:
  // stage target was last READ before the barrier every wave just passed.
  f32x4 acc2[3][2];
#pragma unroll
  for (int ch = 0; ch < 3; ch++)
#pragma unroll
    for (int c2 = 0; c2 < 2; c2++) { f32x4 z = {0.f,0.f,0.f,0.f}; acc2[ch][c2] = z; }

  bhalf8 w2n0 = {}, w2n1 = {}, w2c0, w2c1;
  int bcur = 0;

#pragma unroll 1
  for (int p = 0; p < 8; ++p) {
    const int ct0 = 2 * p, ct1 = 2 * p + 1;
    int bn1 = bcur + 1; if (bn1 >= 3) bn1 -= 3;
    int bn2 = bn1 + 1;  if (bn2 >= 3) bn2 -= 3;
    ushort* bufA = &sm.w1st[bcur][0];   // holds ct0
    ushort* bufB = &sm.w1st[bn1][0];    // holds ct1
    ushort* bufC = &sm.w1st[bn2][0];    // free (last read at ct0-1)

    // ---------- even ct0 ----------
    asm volatile("s_waitcnt vmcnt(2)\n\ts_barrier" ::: "memory");

    // W2 B-frag prefetch for pair p (consumed by GEMM2 at pair p+1 — 2-iter distance)
    w2c0 = w2n0; w2c1 = w2n1;
    w2n0 = *(const bhalf8*)(W2s + ((0 * 8 + p) * 64 + lane) * 8);
    w2n1 = *(const bhalf8*)(W2s + ((1 * 8 + p) * 64 + lane) * 8);

    f32x4 c0, c1, c2;
    gemm1(bufA, lane, a0f, a1f, a2f, c0, c1, c2);

    if (p < 7) stage_ct(W1s, bufC, ct0 + 2, wave, lane);

    // GEMM2 for pair p-1 — independent MFMAs cover c0..c2 result latency
    if (p >= 1) {
      bhalf8 hf0 = *(const bhalf8*)(pw + (0 * 16 + r) * PPITCH + q * 8);
      bhalf8 hf1 = *(const bhalf8*)(pw + (1 * 16 + r) * PPITCH + q * 8);
      bhalf8 hf2 = *(const bhalf8*)(pw + (2 * 16 + r) * PPITCH + q * 8);
      acc2[0][0] = __builtin_amdgcn_mfma_f32_16x16x32_bf16(hf0, w2c0, acc2[0][0], 0, 0, 0);
      acc2[1][0] = __builtin_amdgcn_mfma_f32_16x16x32_bf16(hf1, w2c0, acc2[1][0], 0, 0, 0);
      acc2[2][0] = __builtin_amdgcn_mfma_f32_16x16x32_bf16(hf2, w2c0, acc2[2][0], 0, 0, 0);
      acc2[0][1] = __builtin_amdgcn_mfma_f32_16x16x32_bf16(hf0, w2c1, acc2[0][1], 0, 0, 0);
      acc2[1][1] = __builtin_amdgcn_mfma_f32_16x16x32_bf16(hf1, w2c1, acc2[1][1], 0, 0, 0);
      acc2[2][1] = __builtin_amdgcn_mfma_f32_16x16x32_bf16(hf2, w2c1, acc2[2][1], 0, 0, 0);
    }

    chain(pw, sm.b1e[ct0 * 16 + r], q, r, c0, c1, c2);          // cols 0..15

    // ---------- odd ct1 ----------
    asm volatile("s_waitcnt vmcnt(2)\n\ts_barrier" ::: "memory");

    f32x4 d0, d1, d2;
    gemm1(bufB, lane, a0f, a1f, a2f, d0, d1, d2);

    if (p < 7) stage_ct(W1s, bufA, ct1 + 2, wave, lane);        // bufA free post-barrier

    chain(pw, sm.b1e[ct1 * 16 + r], q, 16 + r, d0, d1, d2);     // cols 16..31

    bcur = bn2;
  }
  // final GEMM2 (pair 7) — frags in w2n
  {
    bhalf8 hf0 = *(const bhalf8*)(pw + (0 * 16 + r) * PPITCH + q * 8);
    bhalf8 hf1 = *(const bhalf8*)(pw + (1 * 16 + r) * PPITCH + q * 8);
    bhalf8 hf2 = *(const bhalf8*)(pw + (2 * 16 + r) * PPITCH + q * 8);
    acc2[0][0] = __builtin_amdgcn_mfma_f32_16x16x32_bf16(hf0, w2n0, acc2[0][0], 0, 0, 0);
    acc2[1][0] = __builtin_amdgcn_mfma_f32_16x16x32_bf16(hf1, w2n0, acc2[1][0], 0, 0, 0);
    acc2[2][0] = __builtin_amdgcn_mfma_f32_16x16x32_bf16(hf2, w2n0, acc2[2][0], 0, 0, 0);
    acc2[0][1] = __builtin_amdgcn_mfma_f32_16x16x32_bf16(hf0, w2n1, acc2[0][1], 0, 0, 0);
    acc2[1][1] = __builtin_amdgcn_mfma_f32_16x16x32_bf16(hf1, w2n1, acc2[1][1], 0, 0, 0);
    acc2[2][1] = __builtin_amdgcn_mfma_f32_16x16x32_bf16(hf2, w2n1, acc2[2][1], 0, 0, 0);
  }

  // ---- epilogue: angles, sin/cos, coupling via MFMA, physics ----
  float dv[2][4], dt[2][4], dtt[2][4], sn[2][4], cs[2][4], Pv[2][4];
#pragma unroll
  for (int c2 = 0; c2 < 2; c2++) {
    int b = c2 * 16 + r;
    float b2v = sm.b2c[b];
#pragma unroll
    for (int i = 0; i < 4; i++) {
      int n = s0 + q * 4 + i;
      Pv[c2][i] = LD<B16>(powerP, n * NB + b);
      dv[c2][i]  = acc2[0][c2][i] + b2v;
      dt[c2][i]  = acc2[1][c2][i];
      dtt[c2][i] = acc2[2][c2][i];
      __sincosf(dv[c2][i], &sn[c2][i], &cs[c2][i]);
      // reuse pair rows: sin -> rows 0..15, cos -> rows 16..31 (after last pair read)
      pw[(q * 4 + i) * PPITCH + b]        = trunc1(sn[c2][i]);
      pw[(16 + q * 4 + i) * PPITCH + b]   = trunc1(cs[c2][i]);
      ST<B16>(outP, n * NB + b, dv[c2][i]);
      ST<B16>(outP, NPTS * NB + n * NB + b, dt[c2][i]);
    }
  }
  // coupling: C = cos @ lam^T, S = sin @ lam^T  (16x32 @ 32x32 via 16x16x32 MFMA)
  bhalf8 snA = *(const bhalf8*)(pw + r * PPITCH + q * 8);
  bhalf8 csA = *(const bhalf8*)(pw + (16 + r) * PPITCH + q * 8);
  f32x4 accC[2], accS[2];
#pragma unroll
  for (int c2 = 0; c2 < 2; c2++) {
    bhalf8 lt = *(const bhalf8*)(sm.lamTf + (c2 * 64 + lane) * 8);
    f32x4 z = {0.f,0.f,0.f,0.f};
    accC[c2] = __builtin_amdgcn_mfma_f32_16x16x32_bf16(csA, lt, z, 0, 0, 0);
    accS[c2] = __builtin_amdgcn_mfma_f32_16x16x32_bf16(snA, lt, z, 0, 0, 0);
  }
#pragma unroll
  for (int c2 = 0; c2 < 2; c2++) {
    int b = c2 * 16 + r;
    float lm = sm.lamMc[b], ld = sm.lamDc[b];
#pragma unroll
    for (int i = 0; i < 4; i++) {
      float conn = sn[c2][i] * accC[c2][i] - cs[c2][i] * accS[c2][i];
      float phys = lm * dtt[c2][i] + ld * dt[c2][i] + conn - Pv[c2][i];
      int n = s0 + q * 4 + i;
      ST<B16>(outP, 2 * NPTS * NB + n * NB + b, phys);
    }
  }
}

// (256,3): W1 double-buffer regs (64) moved to block-shared LDS ring; unified
// reg need should now fit the ~170 cap -> 3 waves/SIMD (was 2). If this spills,
// revert to (256,2).
__global__ __launch_bounds__(256, 3)
void pinn_kernel(const void* timeP, const void* powerP,
                 const void* W0, const void* b0,
                 const void* b1, const void* b2,
                 const void* lam_m, const void* lam_d,
                 const void* lam_b, const void* bwi,
                 const void* W1_for_detect,
                 const ushort* __restrict__ W1s, void* outP) {
  __shared__ Smem sm;
  if (detect_bf16(W1_for_detect))
    pinn_body<true>(sm, timeP, powerP, W0, b0, b1, b2, lam_m, lam_d, lam_b, bwi,
                    W1s, outP);
  else
    pinn_body<false>(sm, timeP, powerP, W0, b0, b1, b2, lam_m, lam_d, lam_b, bwi,
                     W1s, outP);
}

extern "C" void kernel_launch(void* const* d_in, const int* in_sizes, int n_in,
                              void* d_out, int out_size, void* d_ws, size_t ws_size,
                              hipStream_t stream) {
  const void* timeP  = d_in[0];
  const void* powerP = d_in[1];
  const void* W0     = d_in[2];
  const void* b0     = d_in[3];
  const void* W1     = d_in[4];
  const void* b1     = d_in[5];
  const void* W2     = d_in[6];
  const void* b2     = d_in[7];
  const void* lam_m  = d_in[8];
  const void* lam_d  = d_in[9];
  const void* lam_b  = d_in[10];
  const void* bwi    = d_in[11];

  ushort* W1s = (ushort*)d_ws;            // W1 frags 128 KB; W2 frags at +65536
  ushort* W2s = W1s + H * H;

  swz_kernel<<<288, 256, 0, stream>>>(W1, W2, W1s, W2s);
  pinn_kernel<<<1024, 256, 0, stream>>>(timeP, powerP, W0, b0, b1, b2,
                                        lam_m, lam_d, lam_b, bwi, W1,
                                        W1s, d_out);
  (void)W2s;
}

// Round 3
// 126.390 us; speedup vs baseline: 1.5808x; 1.5808x over previous
//
#include <hip/hip_runtime.h>

#define NPTS 65536
#define NB 32
#define H 256
#define K2E 2.8853900817779268f   // 2*log2(e): tanh(z)=1-2/(exp2(K2E*z)+1)

typedef __attribute__((ext_vector_type(8))) short bhalf8;   // 8 bf16 = 4 VGPRs
typedef __attribute__((ext_vector_type(4))) float f32x4;

union BHU { bhalf8 h; uint u[4]; };

__device__ __forceinline__ float bf2f(ushort u) {
  union { uint x; float f; } c; c.x = ((uint)u) << 16; return c.f;
}
__device__ __forceinline__ ushort f2bf(float f) {            // RNE (final outputs only)
  uint x = __float_as_uint(f);
  uint r = x + 0x7FFFu + ((x >> 16) & 1u);
  return (ushort)(r >> 16);
}
__device__ __forceinline__ uint packrne(float a, float b) {
  return (uint)f2bf(a) | ((uint)f2bf(b) << 16);
}
// truncating bf16 — MFMA inputs / LDS intermediates only
__device__ __forceinline__ ushort trunc1(float f) {
  return (ushort)(__float_as_uint(f) >> 16);
}
__device__ __forceinline__ uint packtr(float a, float b) {
  return (__float_as_uint(a) >> 16) | (__float_as_uint(b) & 0xFFFF0000u);
}
// tanh with pre-folded 2*log2e arg: v_exp + v_add + v_rcp + v_fma (no div sequence!)
__device__ __forceinline__ float tanh_pf(float z2e) {
  float e = exp2f(z2e);
  float r = __builtin_amdgcn_rcpf(e + 1.0f);
  return fmaf(-2.0f, r, 1.0f);
}

// dtype detect from W1 bit pattern (wave-uniform)
__device__ __forceinline__ bool detect_bf16(const void* W1) {
  const uint4* p = (const uint4*)W1;
  int cnt = 0;
#pragma unroll
  for (int i = 0; i < 8; i++) {
    uint4 v = p[i];
    uint d[4] = {v.x, v.y, v.z, v.w};
#pragma unroll
    for (int k = 0; k < 4; k++) {
      int e = (d[k] >> 7) & 0xFF;                 // exponent of low halfword
      cnt += (e >= 0x70 && e <= 0x7E) ? 1 : 0;
    }
  }
  return cnt >= 16;
}

template<bool B16> __device__ __forceinline__ float LD(const void* p, int i) {
  if constexpr (B16) return bf2f(((const ushort*)p)[i]);
  else               return ((const float*)p)[i];
}
template<bool B16> __device__ __forceinline__ void ST(void* p, int i, float v) {
  if constexpr (B16) ((ushort*)p)[i] = f2bf(v);
  else               ((float*)p)[i] = v;
}

// Pre-swizzle W1 [256][256], W2 [256][32] into MFMA B-frag order (bf16):
// frag(ct,kk): lane l=q*16+r holds B[kk*32+q*8+j][ct*16+r], j=0..7.
__global__ void swz_kernel(const void* W1, const void* W2,
                           ushort* __restrict__ W1s, ushort* __restrict__ W2s) {
  int gid = blockIdx.x * 256 + threadIdx.x;
  bool b16 = detect_bf16(W1);
  if (gid < 65536) {
    int r = gid & 15, q = (gid >> 4) & 3, j = (gid >> 6) & 7;
    int kk = (gid >> 9) & 7, ct = gid >> 12;
    int src = (kk * 32 + q * 8 + j) * H + ct * 16 + r;
    int dst = ((ct * 8 + kk) * 64 + q * 16 + r) * 8 + j;
    float v = b16 ? bf2f(((const ushort*)W1)[src]) : ((const float*)W1)[src];
    W1s[dst] = f2bf(v);
  } else {
    int g2 = gid - 65536;
    int r = g2 & 15, q = (g2 >> 4) & 3, j = (g2 >> 6) & 7;
    int kk = (g2 >> 9) & 7, ct = (g2 >> 12) & 1;
    int src = (kk * 32 + q * 8 + j) * NB + ct * 16 + r;
    int dst = ((ct * 8 + kk) * 64 + q * 16 + r) * 8 + j;
    float v = b16 ? bf2f(((const ushort*)W2)[src]) : ((const float*)W2)[src];
    W2s[dst] = f2bf(v);
  }
}

#define PPITCH 40    // bf16 cols: 80B rows, b128-aligned

// LDS layout:
//   pairw: wave-private h1 chunk (rows 0..31 reused for sin/cos in epilogue)
//   w1st : 3-buffer ring of one-ct W1 B-frag chunks (8KB each), block-shared,
//          filled by global_load_lds (linear layout == frag layout, rule-21 OK)
struct Smem {
  alignas(16) ushort pairw[4][48 * PPITCH];  // 15360 B
  alignas(16) ushort w1st[3][4096];          // 24576 B
  alignas(16) ushort lamTf[2 * 64 * 8];      //  2048 B lambda^T B-frags
  alignas(16) float  w0d[H], w0e[H], b0e[H], b1e[H]; // 4096 B (w0d = 0.1*w0 pre-folded)
  alignas(16) float  b2c[NB], lamMc[NB], lamDc[NB]; // 384 B
};                                           // 46464 B -> 3 blocks/CU LDS-wise

// Stage one ct's 8KB W1-frag chunk into an LDS ring buffer.
// Dest is wave-uniform base (HW adds lane*16B); src is per-lane. 2 issues/wave.
__device__ __forceinline__ void stage_ct(const ushort* __restrict__ W1s,
                                         ushort* buf, int ct, int wave, int lane) {
#pragma unroll
  for (int c = 0; c < 2; c++) {
    const ushort* src = W1s + ct * 4096 + (wave * 2 + c) * 512 + lane * 8;
    ushort* dst = buf + (wave * 2 + c) * 512;   // wave-uniform
    __builtin_amdgcn_global_load_lds(
        (const __attribute__((address_space(1))) unsigned int*)src,
        (__attribute__((address_space(3))) unsigned int*)dst, 16, 0, 0);
  }
}

// GEMM1 for one ct. B-frags streamed through bf[4] (two half-passes) to cut
// transient register peak 32->16: total live-set must land <=~170 so the
// allocator gives 3 waves/SIMD on its own under the safe (256,2) bound.
__device__ __forceinline__ void gemm1(const ushort* __restrict__ buf, int lane,
                                      const bhalf8* a0f, const bhalf8* a1f,
                                      const bhalf8* a2f,
                                      f32x4& c0, f32x4& c1, f32x4& c2) {
  f32x4 z = {0.f, 0.f, 0.f, 0.f};
  c0 = z; c1 = z; c2 = z;
#pragma unroll
  for (int h = 0; h < 2; h++) {
    bhalf8 bf[4];
#pragma unroll
    for (int kk = 0; kk < 4; kk++)
      bf[kk] = *(const bhalf8*)(buf + ((h * 4 + kk) * 64 + lane) * 8);
    __builtin_amdgcn_s_setprio(1);
#pragma unroll
    for (int kk = 0; kk < 4; kk++) {
      c0 = __builtin_amdgcn_mfma_f32_16x16x32_bf16(a0f[h * 4 + kk], bf[kk], c0, 0, 0, 0);
      c1 = __builtin_amdgcn_mfma_f32_16x16x32_bf16(a1f[h * 4 + kk], bf[kk], c1, 0, 0, 0);
      c2 = __builtin_amdgcn_mfma_f32_16x16x32_bf16(a2f[h * 4 + kk], bf[kk], c2, 0, 0, 0);
    }
    __builtin_amdgcn_s_setprio(0);
  }
}

// tanh chain for one ct -> pw column lc
__device__ __forceinline__ void chain(ushort* pw, float b1v, int q, int lc,
                                      const f32x4& c0, const f32x4& c1,
                                      const f32x4& c2) {
#pragma unroll
  for (int i = 0; i < 4; i++) {
    float hv  = tanh_pf(fmaf(c0[i], K2E, b1v));
    float s2  = 1.0f - hv * hv;
    float hd  = s2 * c1[i];
    float hdd = s2 * c2[i] - 2.0f * hv * hd * c1[i];
    int row = q * 4 + i;
    pw[row * PPITCH + lc]        = trunc1(hv);
    pw[(16 + row) * PPITCH + lc] = trunc1(hd);
    pw[(32 + row) * PPITCH + lc] = trunc1(hdd);
  }
}

template<bool B16>
__device__ void pinn_body(Smem& sm,
                          const void* timeP, const void* powerP,
                          const void* W0, const void* b0,
                          const void* b1, const void* b2,
                          const void* lam_m, const void* lam_d,
                          const void* lam_b, const void* bwi,
                          const ushort* __restrict__ W1s, void* outP) {
  const int tid = threadIdx.x;
  const int wave = tid >> 6, lane = tid & 63;
  const int q = lane >> 4, r = lane & 15;
  const ushort* W2s = W1s + H * H;

  // issue ring prologue stages first — latency hides under the whole preamble
  stage_ct(W1s, &sm.w1st[0][0], 0, wave, lane);
  stage_ct(W1s, &sm.w1st[1][0], 1, wave, lane);

  // ================= preamble (one barrier) =================
  if (tid < 128) {   // lambda^T B-frags: lane holds lam_b[ct*16+r][q*8+j]
    int ct = tid >> 6, l2 = tid & 63, qq = l2 >> 4, rr = l2 & 15;
    BHU t;
#pragma unroll
    for (int j = 0; j < 8; j += 2)
      t.u[j >> 1] = packrne(LD<B16>(lam_b, (ct * 16 + rr) * NB + qq * 8 + j),
                            LD<B16>(lam_b, (ct * 16 + rr) * NB + qq * 8 + j + 1));
    *(bhalf8*)(sm.lamTf + tid * 8) = t.h;
  }
  if (tid < H) {
    float w0v = LD<B16>(W0, tid);
    sm.w0d[tid] = 0.1f * w0v;          // pre-fold the 2/TMAX chain-rule factor
    sm.w0e[tid] = K2E * w0v;
    sm.b0e[tid] = K2E * LD<B16>(b0, tid);
    sm.b1e[tid] = K2E * LD<B16>(b1, tid);
  }
  if (tid < NB) {
    sm.b2c[tid]   = LD<B16>(b2, tid);
    sm.lamMc[tid] = LD<B16>(lam_m, tid) * LD<B16>(bwi, tid);
    sm.lamDc[tid] = LD<B16>(lam_d, tid);
  }
  __syncthreads();   // full drain once — prologue stages complete here too

  // ================= per-wave sample tile =================
  const int s0 = (blockIdx.x * 4 + wave) * 16;
  ushort* pw = &sm.pairw[wave][0];

  float t = LD<B16>(timeP, s0 + r);
  float x = t * 0.1f - 1.0f;               // 2t/TMAX - 1, TMAX = 20

  // ---- A-frags in registers: lane holds Ach[r][kk*32+q*8+j] ----
  bhalf8 a0f[8], a1f[8], a2f[8];
#pragma unroll
  for (int kk = 0; kk < 8; kk++) {
    int k0 = kk * 32 + q * 8;
    float4 wA = *(const float4*)&sm.w0d[k0];
    float4 wB = *(const float4*)&sm.w0d[k0 + 4];
    float4 eA = *(const float4*)&sm.w0e[k0];
    float4 eB = *(const float4*)&sm.w0e[k0 + 4];
    float4 bA = *(const float4*)&sm.b0e[k0];
    float4 bB = *(const float4*)&sm.b0e[k0 + 4];
    float w0dv[8] = {wA.x, wA.y, wA.z, wA.w, wB.x, wB.y, wB.z, wB.w};
    float w0ev[8] = {eA.x, eA.y, eA.z, eA.w, eB.x, eB.y, eB.z, eB.w};
    float b0ev[8] = {bA.x, bA.y, bA.z, bA.w, bB.x, bB.y, bB.z, bB.w};
    BHU t0, t1, t2;
    float vv[8], d1v[8], d2v[8];
#pragma unroll
    for (int j = 0; j < 8; j++) {
      float v = tanh_pf(fmaf(x, w0ev[j], b0ev[j]));
      float cc = w0dv[j];                       // = w0*0.1 (pre-folded)
      float s2 = 1.0f - v * v;
      vv[j] = v; d1v[j] = s2 * cc; d2v[j] = -2.0f * v * d1v[j] * cc;
    }
#pragma unroll
    for (int j = 0; j < 8; j += 2) {
      t0.u[j >> 1] = packtr(vv[j], vv[j + 1]);
      t1.u[j >> 1] = packtr(d1v[j], d1v[j + 1]);
      t2.u[j >> 1] = packtr(d2v[j], d2v[j + 1]);
    }
    a0f[kk] = t0.h; a1f[kk] = t1.h; a2f[kk] = t2.h;
  }

  // ---- fused GEMM1 -> tanh chain -> GEMM2 over LDS W1 ring ----
  // Sync discipline (T3/T4): one {vmcnt(2); s_barrier} per ct, counted — never
  // drains the stage queue. 3-buffer rotation makes a single barrier race-free:
  // stage target was last READ before the barrier every wave just passed.
  f32x4 acc2[3][2];
#pragma unroll
  for (int ch = 0; ch < 3; ch++)
#pragma unroll
    for (int c2 = 0; c2 < 2; c2++) { f32x4 z = {0.f,0.f,0.f,0.f}; acc2[ch][c2] = z; }

  bhalf8 w2n0 = {}, w2n1 = {}, w2c0, w2c1;
  int bcur = 0;

#pragma unroll 1
  for (int p = 0; p < 8; ++p) {
    const int ct0 = 2 * p, ct1 = 2 * p + 1;
    int bn1 = bcur + 1; if (bn1 >= 3) bn1 -= 3;
    int bn2 = bn1 + 1;  if (bn2 >= 3) bn2 -= 3;
    ushort* bufA = &sm.w1st[bcur][0];   // holds ct0
    ushort* bufB = &sm.w1st[bn1][0];    // holds ct1
    ushort* bufC = &sm.w1st[bn2][0];    // free (last read at ct0-1)

    // ---------- even ct0 ----------
    asm volatile("s_waitcnt vmcnt(2)\n\ts_barrier" ::: "memory");

    // W2 B-frag prefetch for pair p (consumed by GEMM2 at pair p+1 — 2-iter distance)
    w2c0 = w2n0; w2c1 = w2n1;
    w2n0 = *(const bhalf8*)(W2s + ((0 * 8 + p) * 64 + lane) * 8);
    w2n1 = *(const bhalf8*)(W2s + ((1 * 8 + p) * 64 + lane) * 8);

    f32x4 c0, c1, c2;
    gemm1(bufA, lane, a0f, a1f, a2f, c0, c1, c2);

    if (p < 7) stage_ct(W1s, bufC, ct0 + 2, wave, lane);

    // GEMM2 for pair p-1 — independent MFMAs cover c0..c2 result latency
    if (p >= 1) {
      bhalf8 hf0 = *(const bhalf8*)(pw + (0 * 16 + r) * PPITCH + q * 8);
      bhalf8 hf1 = *(const bhalf8*)(pw + (1 * 16 + r) * PPITCH + q * 8);
      bhalf8 hf2 = *(const bhalf8*)(pw + (2 * 16 + r) * PPITCH + q * 8);
      acc2[0][0] = __builtin_amdgcn_mfma_f32_16x16x32_bf16(hf0, w2c0, acc2[0][0], 0, 0, 0);
      acc2[1][0] = __builtin_amdgcn_mfma_f32_16x16x32_bf16(hf1, w2c0, acc2[1][0], 0, 0, 0);
      acc2[2][0] = __builtin_amdgcn_mfma_f32_16x16x32_bf16(hf2, w2c0, acc2[2][0], 0, 0, 0);
      acc2[0][1] = __builtin_amdgcn_mfma_f32_16x16x32_bf16(hf0, w2c1, acc2[0][1], 0, 0, 0);
      acc2[1][1] = __builtin_amdgcn_mfma_f32_16x16x32_bf16(hf1, w2c1, acc2[1][1], 0, 0, 0);
      acc2[2][1] = __builtin_amdgcn_mfma_f32_16x16x32_bf16(hf2, w2c1, acc2[2][1], 0, 0, 0);
    }

    chain(pw, sm.b1e[ct0 * 16 + r], q, r, c0, c1, c2);          // cols 0..15

    // ---------- odd ct1 ----------
    asm volatile("s_waitcnt vmcnt(2)\n\ts_barrier" ::: "memory");

    f32x4 d0, d1, d2;
    gemm1(bufB, lane, a0f, a1f, a2f, d0, d1, d2);

    if (p < 7) stage_ct(W1s, bufA, ct1 + 2, wave, lane);        // bufA free post-barrier

    chain(pw, sm.b1e[ct1 * 16 + r], q, 16 + r, d0, d1, d2);     // cols 16..31

    bcur = bn2;
  }
  // final GEMM2 (pair 7) — frags in w2n
  {
    bhalf8 hf0 = *(const bhalf8*)(pw + (0 * 16 + r) * PPITCH + q * 8);
    bhalf8 hf1 = *(const bhalf8*)(pw + (1 * 16 + r) * PPITCH + q * 8);
    bhalf8 hf2 = *(const bhalf8*)(pw + (2 * 16 + r) * PPITCH + q * 8);
    acc2[0][0] = __builtin_amdgcn_mfma_f32_16x16x32_bf16(hf0, w2n0, acc2[0][0], 0, 0, 0);
    acc2[1][0] = __builtin_amdgcn_mfma_f32_16x16x32_bf16(hf1, w2n0, acc2[1][0], 0, 0, 0);
    acc2[2][0] = __builtin_amdgcn_mfma_f32_16x16x32_bf16(hf2, w2n0, acc2[2][0], 0, 0, 0);
    acc2[0][1] = __builtin_amdgcn_mfma_f32_16x16x32_bf16(hf0, w2n1, acc2[0][1], 0, 0, 0);
    acc2[1][1] = __builtin_amdgcn_mfma_f32_16x16x32_bf16(hf1, w2n1, acc2[1][1], 0, 0, 0);
    acc2[2][1] = __builtin_amdgcn_mfma_f32_16x16x32_bf16(hf2, w2n1, acc2[2][1], 0, 0, 0);
  }

  // ---- epilogue: angles, sin/cos, coupling via MFMA, physics ----
  float dv[2][4], dt[2][4], dtt[2][4], sn[2][4], cs[2][4], Pv[2][4];
#pragma unroll
  for (int c2 = 0; c2 < 2; c2++) {
    int b = c2 * 16 + r;
    float b2v = sm.b2c[b];
#pragma unroll
    for (int i = 0; i < 4; i++) {
      int n = s0 + q * 4 + i;
      Pv[c2][i] = LD<B16>(powerP, n * NB + b);
      dv[c2][i]  = acc2[0][c2][i] + b2v;
      dt[c2][i]  = acc2[1][c2][i];
      dtt[c2][i] = acc2[2][c2][i];
      __sincosf(dv[c2][i], &sn[c2][i], &cs[c2][i]);
      // reuse pair rows: sin -> rows 0..15, cos -> rows 16..31 (after last pair read)
      pw[(q * 4 + i) * PPITCH + b]        = trunc1(sn[c2][i]);
      pw[(16 + q * 4 + i) * PPITCH + b]   = trunc1(cs[c2][i]);
      ST<B16>(outP, n * NB + b, dv[c2][i]);
      ST<B16>(outP, NPTS * NB + n * NB + b, dt[c2][i]);
    }
  }
  // coupling: C = cos @ lam^T, S = sin @ lam^T  (16x32 @ 32x32 via 16x16x32 MFMA)
  bhalf8 snA = *(const bhalf8*)(pw + r * PPITCH + q * 8);
  bhalf8 csA = *(const bhalf8*)(pw + (16 + r) * PPITCH + q * 8);
  f32x4 accC[2], accS[2];
#pragma unroll
  for (int c2 = 0; c2 < 2; c2++) {
    bhalf8 lt = *(const bhalf8*)(sm.lamTf + (c2 * 64 + lane) * 8);
    f32x4 z = {0.f,0.f,0.f,0.f};
    accC[c2] = __builtin_amdgcn_mfma_f32_16x16x32_bf16(csA, lt, z, 0, 0, 0);
    accS[c2] = __builtin_amdgcn_mfma_f32_16x16x32_bf16(snA, lt, z, 0, 0, 0);
  }
#pragma unroll
  for (int c2 = 0; c2 < 2; c2++) {
    int b = c2 * 16 + r;
    float lm = sm.lamMc[b], ld = sm.lamDc[b];
#pragma unroll
    for (int i = 0; i < 4; i++) {
      float conn = sn[c2][i] * accC[c2][i] - cs[c2][i] * accS[c2][i];
      float phys = lm * dtt[c2][i] + ld * dt[c2][i] + conn - Pv[c2][i];
      int n = s0 + q * 4 + i;
      ST<B16>(outP, 2 * NPTS * NB + n * NB + b, phys);
    }
  }
}

// (256,2): spill-proof cap (round-1's (256,3) spilled: WRITE 24.5->68.6MB).
// 2nd arg is a MIN-waves promise; with the bf[4]-streamed GEMM1 the live-set
// should land <=~170 and the allocator grants 3 waves/SIMD on its own.
__global__ __launch_bounds__(256, 2)
void pinn_kernel(const void* timeP, const void* powerP,
                 const void* W0, const void* b0,
                 const void* b1, const void* b2,
                 const void* lam_m, const void* lam_d,
                 const void* lam_b, const void* bwi,
                 const void* W1_for_detect,
                 const ushort* __restrict__ W1s, void* outP) {
  __shared__ Smem sm;
  if (detect_bf16(W1_for_detect))
    pinn_body<true>(sm, timeP, powerP, W0, b0, b1, b2, lam_m, lam_d, lam_b, bwi,
                    W1s, outP);
  else
    pinn_body<false>(sm, timeP, powerP, W0, b0, b1, b2, lam_m, lam_d, lam_b, bwi,
                     W1s, outP);
}

extern "C" void kernel_launch(void* const* d_in, const int* in_sizes, int n_in,
                              void* d_out, int out_size, void* d_ws, size_t ws_size,
                              hipStream_t stream) {
  const void* timeP  = d_in[0];
  const void* powerP = d_in[1];
  const void* W0     = d_in[2];
  const void* b0     = d_in[3];
  const void* W1     = d_in[4];
  const void* b1     = d_in[5];
  const void* W2     = d_in[6];
  const void* b2     = d_in[7];
  const void* lam_m  = d_in[8];
  const void* lam_d  = d_in[9];
  const void* lam_b  = d_in[10];
  const void* bwi    = d_in[11];

  ushort* W1s = (ushort*)d_ws;            // W1 frags 128 KB; W2 frags at +65536
  ushort* W2s = W1s + H * H;

  swz_kernel<<<288, 256, 0, stream>>>(W1, W2, W1s, W2s);
  pinn_kernel<<<1024, 256, 0, stream>>>(timeP, powerP, W0, b0, b1, b2,
                                        lam_m, lam_d, lam_b, bwi, W1,
                                        W1s, d_out);
  (void)W2s;
}